// Round 20
// baseline (232.573 us; speedup 1.0000x reference)
//
#include <hip/hip_runtime.h>
#include <hip/hip_bf16.h>

#define NTOK 4096   // B*T
#define DDIM 1024
#define NEXP 8
#define FDIM 2048
#define CAP  4096   // max assignments per expert (list storage)
#define RTOK 16     // tokens per router block (512 threads, quarter-D split)
#define MTT  10     // m-tiles per expert (1280-row capacity; cnt~1024+-30, +8.5 sigma)

typedef float f32x4 __attribute__((ext_vector_type(4)));
typedef short s16x8 __attribute__((ext_vector_type(8)));
typedef short s16x4 __attribute__((ext_vector_type(4)));

__device__ __forceinline__ unsigned short f2bf(float f) {
  unsigned int u = __float_as_uint(f);
  unsigned int r = u + 0x7fffu + ((u >> 16) & 1u);
  return (unsigned short)(r >> 16);
}

__device__ __forceinline__ void gload16(const void* g, void* l) {
  __builtin_amdgcn_global_load_lds(
      (__attribute__((address_space(1))) unsigned int*)(g),
      (__attribute__((address_space(3))) unsigned int*)(l), 16, 0, 0);
}

// 512-thread transpose tile body (R19 w2-version, proven): src [R][C] f32 -> dst [C][R] bf16
// Block: 64 src-cols (c0) x 256 src-rows (r0b), double-buffered [2][64][65] f32 tile.
// Load: 2 passes of 32 rows (float4); store: 1 pass, col=tid>>3, 8 rows (s16x8, 16B).
// Both phases exact 2-way banks (free, m136).
__device__ __forceinline__ void transpose_tile512(const float* __restrict__ s,
                                                  unsigned short* __restrict__ d,
                                                  int R, int C, int c0, int r0b,
                                                  char* smem, int tid) {
  float (*tile)[64][65] = (float(*)[64][65])smem;
  const int lr = tid >> 4, lc = (tid & 15) * 4;     // lr 0..31
  const int sc = tid >> 3, sr = (tid & 7) * 8;      // sc 0..63
  float4 v[2];
  #pragma unroll
  for (int p = 0; p < 2; p++)
    v[p] = *(const float4*)(s + (size_t)(r0b + p * 32 + lr) * C + c0 + lc);
  #pragma unroll
  for (int t = 0; t < 4; t++) {
    const int cur = t & 1;
    #pragma unroll
    for (int p = 0; p < 2; p++) {
      tile[cur][p * 32 + lr][lc]     = v[p].x;
      tile[cur][p * 32 + lr][lc + 1] = v[p].y;
      tile[cur][p * 32 + lr][lc + 2] = v[p].z;
      tile[cur][p * 32 + lr][lc + 3] = v[p].w;
    }
    if (t < 3) {
      #pragma unroll
      for (int p = 0; p < 2; p++)
        v[p] = *(const float4*)(s + (size_t)(r0b + (t + 1) * 64 + p * 32 + lr) * C + c0 + lc);
    }
    __syncthreads();
    const int r0 = r0b + t * 64;
    s16x8 o;
    #pragma unroll
    for (int j = 0; j < 8; j++) o[j] = (short)f2bf(tile[cur][sr + j][sc]);
    *(s16x8*)(d + (size_t)(c0 + sc) * R + r0 + sr) = o;   // 16B coalesced
    __syncthreads();
  }
}

// ================= k_prep (512 thr): router (256 blocks, FIRST) + w1-transpose (1024 blocks) =================
// Router thread = (token t=tid>>5, quarter q=(tid>>3)&3, expert e=tid&7): each computes a
// 256-col fp64 partial -> lgd[t][e][q]; serial chain = 64 iters (4x shorter than R19).
__global__ __launch_bounds__(512)
void k_prep(const float* __restrict__ x, const float* __restrict__ gw,
            const float* __restrict__ w1,
            unsigned short* __restrict__ xb, unsigned short* __restrict__ w1t,
            float* __restrict__ topw, int* __restrict__ elist,
            int* __restrict__ ecnt, int* __restrict__ cnt1,
            float* __restrict__ psum, float* __restrict__ sqsum) {
  __shared__ char smem[56320];   // union: transpose 33,280 | router ~54,100
  const int bid = blockIdx.x, tid = threadIdx.x;

  if (bid >= 256) {
    // ---- w1 transpose: [E][1024][2048] f32 -> w1t [E][2048][1024] bf16
    const int b = bid - 256;
    const int cx = b & 31, ry = (b >> 5) & 3, e = b >> 7;
    transpose_tile512(w1 + (size_t)e * DDIM * FDIM, w1t + (size_t)e * DDIM * FDIM,
                      DDIM, FDIM, cx * 64, ry * 256, smem, tid);
    return;
  }

  // ---- router: 256 blocks x 16 tokens; fp64 accum; emits xb ----
  float (*gwt)[DDIM + 4] = (float(*)[DDIM + 4])smem;          // 32,896 B
  float (*xs)[264]       = (float(*)[264])(smem + 32896);     // 16,896 B ([16][264])
  double (*lgd)[NEXP][4] = (double(*)[NEXP][4])(smem + 49792);// 4,096 B
  float* bps = (float*)(smem + 53888);
  int*   bc  = (int*)(smem + 53920);
  float* bsq = (float*)(smem + 53952);
  const int tok0 = bid * RTOK;

  for (int i = tid; i < DDIM * NEXP; i += 512) {
    int dd = i >> 3, ee = i & 7;
    gwt[ee][dd] = gw[i];
  }
  if (tid < NEXP) { bps[tid] = 0.f; bc[tid] = 0; }
  if (tid == 0) *bsq = 0.f;

  const int t = tid >> 5, q = (tid >> 3) & 3, e = tid & 7;
  double a0 = 0.0, a1 = 0.0, a2 = 0.0, a3 = 0.0;
  for (int c = 0; c < DDIM; c += 256) {
    __syncthreads();
    for (int i = tid; i < RTOK * 64; i += 512) {   // [16][256] chunk, float4 coalesced
      int r = i >> 6, c4 = i & 63;
      float4 v = *(const float4*)(x + (size_t)(tok0 + r) * DDIM + c + c4 * 4);
      *(float4*)&xs[r][c4 * 4] = v;
      s16x4 o;
      o[0] = (short)f2bf(v.x); o[1] = (short)f2bf(v.y);
      o[2] = (short)f2bf(v.z); o[3] = (short)f2bf(v.w);
      *(s16x4*)(xb + (size_t)(tok0 + r) * DDIM + c + c4 * 4) = o;
    }
    __syncthreads();
    if ((c >> 8) == q) {                           // my quarter only: 64 iters total
      #pragma unroll 8
      for (int d4 = 0; d4 < 64; d4++) {
        float4 xv = *(const float4*)&xs[t][d4 * 4];
        float4 gv = *(const float4*)&gwt[e][c + d4 * 4];
        a0 += (double)xv.x * (double)gv.x;
        a1 += (double)xv.y * (double)gv.y;
        a2 += (double)xv.z * (double)gv.z;
        a3 += (double)xv.w * (double)gv.w;
      }
    }
  }
  lgd[t][e][q] = (a0 + a1) + (a2 + a3);
  __syncthreads();

  if (tid < RTOK) {
    int tok = tok0 + tid;
    double acc[NEXP];
    #pragma unroll
    for (int k = 0; k < NEXP; k++)
      acc[k] = ((lgd[tid][k][0] + lgd[tid][k][1]) + lgd[tid][k][2]) + lgd[tid][k][3];
    int i0 = 0; double v0 = acc[0];
    #pragma unroll
    for (int k = 1; k < NEXP; k++) if (acc[k] > v0) { v0 = acc[k]; i0 = k; }
    int i1 = (i0 == 0) ? 1 : 0; double v1 = acc[i1];
    #pragma unroll
    for (int k = 0; k < NEXP; k++) if (k != i0 && acc[k] > v1) { v1 = acc[k]; i1 = k; }
    float w0 = 1.0f / (1.0f + expf((float)(v1 - v0)));   // softmax([v0,v1])[0]
    topw[2*tok] = w0; topw[2*tok + 1] = 1.0f - w0;
    int s0 = atomicAdd(&ecnt[i0], 1); elist[i0*CAP + s0] = 2*tok;
    int s1 = atomicAdd(&ecnt[i1], 1); elist[i1*CAP + s1] = 2*tok + 1;
    atomicAdd(&bc[i0], 1);
    float lm = (float)acc[0];
    #pragma unroll
    for (int k = 1; k < NEXP; k++) lm = fmaxf(lm, (float)acc[k]);
    float pe[NEXP], ps = 0.f, sq = 0.f;
    #pragma unroll
    for (int k = 0; k < NEXP; k++) {
      float le = (float)acc[k];
      pe[k] = expf(le - lm); ps += pe[k];
      sq += le * le;
    }
    float inv = 1.0f / ps;
    #pragma unroll
    for (int k = 0; k < NEXP; k++) atomicAdd(&bps[k], pe[k] * inv);
    atomicAdd(bsq, sq);
  }
  __syncthreads();
  if (tid < NEXP) { atomicAdd(&psum[tid], bps[tid]); atomicAdd(&cnt1[tid], bc[tid]); }
  if (tid == 0) atomicAdd(sqsum, *bsq);
}

// ================= k_gemm1w2: GEMM1 (1280 blocks, FIRST) + w2-transpose (1024 blocks, 512-thr) =================
#define NG1 (16 * MTT * NEXP)   // 1280 GEMM1 blocks
__global__ __launch_bounds__(512)
void k_gemm1w2(const unsigned short* __restrict__ A, const unsigned short* __restrict__ Bt,
               const float* __restrict__ bias, unsigned short* __restrict__ Out,
               const int* __restrict__ elist, const int* __restrict__ ecnt,
               const float* __restrict__ w2, unsigned short* __restrict__ w2t) {
  __shared__ char smem[65536];
  const int bid = blockIdx.x, tid = threadIdx.x;

  if (bid >= NG1) {
    // ---- w2 transpose: [E][2048][1024] f32 -> w2t [E][1024][2048] bf16
    const int b = bid - NG1;
    const int cx = b & 15, ry = (b >> 4) & 7, e = b >> 7;
    transpose_tile512(w2 + (size_t)e * FDIM * DDIM, w2t + (size_t)e * FDIM * DDIM,
                      FDIM, DDIM, cx * 64, ry * 256, smem, tid);
    return;
  }

  // ---- GEMM1 (R7/R17-proven mapping: nt fastest, then mt, then e — NO XCD swizzle) ----
  constexpr int K = DDIM, N = FDIM;
  constexpr int BM = 128, BN = 128, BK = 128, WM = 2, WN = 4;
  constexpr int GX = N / BN;                        // 16
  constexpr int AISS = 4, BISS = 4, MF = 4, NF = 2;
  unsigned char* lsA = (unsigned char*)smem;          // 32 KB
  unsigned char* lsB = (unsigned char*)smem + 32768;  // 32 KB

  const int w = bid;
  const int nt = w % GX;
  const int mt = (w / GX) % MTT;
  const int e  = w / (GX * MTT);

  const int cnt = ecnt[e];
  const int m0 = mt * BM;
  if (m0 >= cnt) return;
  const int rv = min(BM, cnt - m0);
  const int* lst = elist + e * CAP + m0;
  const int wv = tid >> 6, lane = tid & 63;
  const int wm = wv / WN, wn = wv % WN;
  const unsigned short* Be = Bt + (size_t)e * N * K;

  const unsigned short* agp[AISS];
  const unsigned short* bgp[BISS];
  int adst[AISS], bdst[BISS];
  const int cu = tid & 15;
  #pragma unroll
  for (int li = 0; li < AISS; li++) {
    int r = li * 32 + (tid >> 4);
    int rr = (r < rv) ? r : 0;
    int aid = lst[rr];
    int arow = aid >> 1;                            // ROWSHIFT
    agp[li] = A + (size_t)arow * K + (cu ^ (r & 15)) * 8;
    adst[li] = r * 256 + cu * 16;
  }
  #pragma unroll
  for (int li = 0; li < BISS; li++) {
    int r = li * 32 + (tid >> 4);
    bgp[li] = Be + (size_t)(nt * BN + r) * K + (cu ^ (r & 15)) * 8;
    bdst[li] = r * 256 + cu * 16;
  }

  f32x4 acc[MF][NF];
  #pragma unroll
  for (int mi = 0; mi < MF; mi++)
    #pragma unroll
    for (int ni = 0; ni < NF; ni++)
      acc[mi][ni] = (f32x4){0.f, 0.f, 0.f, 0.f};

  constexpr int NK = K / BK;
  for (int t = 0; t < NK; ++t) {
    const int k0 = t * BK;
    #pragma unroll
    for (int li = 0; li < AISS; li++) gload16(agp[li] + k0, &lsA[adst[li]]);
    #pragma unroll
    for (int li = 0; li < BISS; li++) gload16(bgp[li] + k0, &lsB[bdst[li]]);
    __syncthreads();
    #pragma unroll
    for (int ks = 0; ks < 4; ks++) {
      s16x8 af[MF], bf[NF];
      #pragma unroll
      for (int mi = 0; mi < MF; mi++) {
        int row = wm * (BM / WM) + mi * 16 + (lane & 15);
        int c16 = (ks * 4 + (lane >> 4)) ^ (row & 15);
        af[mi] = *(const s16x8*)&lsA[row * 256 + c16 * 16];
      }
      #pragma unroll
      for (int ni = 0; ni < NF; ni++) {
        int row = wn * (BN / WN) + ni * 16 + (lane & 15);
        int c16 = (ks * 4 + (lane >> 4)) ^ (row & 15);
        bf[ni] = *(const s16x8*)&lsB[row * 256 + c16 * 16];
      }
      #pragma unroll
      for (int mi = 0; mi < MF; mi++)
        #pragma unroll
        for (int ni = 0; ni < NF; ni++)
          acc[mi][ni] = __builtin_amdgcn_mfma_f32_16x16x32_bf16(af[mi], bf[ni], acc[mi][ni], 0, 0, 0);
    }
    __syncthreads();
  }

  const int g4 = (lane >> 4) * 4, cn = lane & 15;
  #pragma unroll
  for (int mi = 0; mi < MF; mi++) {
    #pragma unroll
    for (int reg = 0; reg < 4; reg++) {
      int r = wm * (BM / WM) + mi * 16 + g4 + reg;
      if (r < rv) {
        int aid = lst[r];
        #pragma unroll
        for (int ni = 0; ni < NF; ni++) {
          int n = nt * BN + wn * (BN / WN) + ni * 16 + cn;
          float v = acc[mi][ni][reg] + bias[(size_t)e * N + n];
          v = 0.5f * v * (1.0f + erff(v * 0.70710678118654752f));  // exact gelu
          Out[(size_t)aid * N + n] = f2bf(v);
        }
      }
    }
  }
}

// ---------------- GEMM2 (R16/R18-proven: XCD-chunked swizzle — expert-per-XCD, L2-resident B) ----------------
template<int K, int N, bool GELU, bool ROWSHIFT>
__global__ __launch_bounds__(512)
void k_gemm(const unsigned short* __restrict__ A, const unsigned short* __restrict__ Bt,
            const float* __restrict__ bias, void* __restrict__ Out,
            const int* __restrict__ elist, const int* __restrict__ ecnt) {
  constexpr int BM = 128, BN = 128, BK = 128, WM = 2, WN = 4;
  constexpr int GX = N / BN;
  constexpr int TOT = GX * MTT * NEXP;     // 640, % 8 == 0 (bijective)
  constexpr int CHUNK = TOT / 8;           // 80 = one expert's tile set
  constexpr int AISS = BM / 32, BISS = BN / 32;
  constexpr int MF = BM / WM / 16, NF = BN / WN / 16;
  __shared__ unsigned char lsA[BM * 256];
  __shared__ unsigned char lsB[BN * 256];

  const int w = blockIdx.x;
  const int swz = (w & 7) * CHUNK + (w >> 3);
  const int e = swz / CHUNK;
  const int loc = swz % CHUNK;
  const int mt = loc % MTT, nt = loc / MTT;

  const int cnt = ecnt[e];
  const int m0 = mt * BM;
  if (m0 >= cnt) return;
  const int rv = min(BM, cnt - m0);
  const int* lst = elist + e * CAP + m0;
  const int tid = threadIdx.x, wv = tid >> 6, lane = tid & 63;
  const int wm = wv / WN, wn = wv % WN;
  const unsigned short* Be = Bt + (size_t)e * N * K;

  const unsigned short* agp[AISS];
  const unsigned short* bgp[BISS];
  int adst[AISS], bdst[BISS];
  const int cu = tid & 15;
  #pragma unroll
  for (int li = 0; li < AISS; li++) {
    int r = li * 32 + (tid >> 4);
    int rr = (r < rv) ? r : 0;
    int aid = lst[rr];
    int arow = ROWSHIFT ? (aid >> 1) : aid;
    agp[li] = A + (size_t)arow * K + (cu ^ (r & 15)) * 8;
    adst[li] = r * 256 + cu * 16;
  }
  #pragma unroll
  for (int li = 0; li < BISS; li++) {
    int r = li * 32 + (tid >> 4);
    bgp[li] = Be + (size_t)(nt * BN + r) * K + (cu ^ (r & 15)) * 8;
    bdst[li] = r * 256 + cu * 16;
  }

  f32x4 acc[MF][NF];
  #pragma unroll
  for (int mi = 0; mi < MF; mi++)
    #pragma unroll
    for (int ni = 0; ni < NF; ni++)
      acc[mi][ni] = (f32x4){0.f, 0.f, 0.f, 0.f};

  constexpr int NK = K / BK;
  for (int t = 0; t < NK; ++t) {
    const int k0 = t * BK;
    #pragma unroll
    for (int li = 0; li < AISS; li++) gload16(agp[li] + k0, &lsA[adst[li]]);
    #pragma unroll
    for (int li = 0; li < BISS; li++) gload16(bgp[li] + k0, &lsB[bdst[li]]);
    __syncthreads();
    #pragma unroll
    for (int ks = 0; ks < 4; ks++) {
      s16x8 af[MF], bf[NF];
      #pragma unroll
      for (int mi = 0; mi < MF; mi++) {
        int row = wm * (BM / WM) + mi * 16 + (lane & 15);
        int c16 = (ks * 4 + (lane >> 4)) ^ (row & 15);
        af[mi] = *(const s16x8*)&lsA[row * 256 + c16 * 16];
      }
      #pragma unroll
      for (int ni = 0; ni < NF; ni++) {
        int row = wn * (BN / WN) + ni * 16 + (lane & 15);
        int c16 = (ks * 4 + (lane >> 4)) ^ (row & 15);
        bf[ni] = *(const s16x8*)&lsB[row * 256 + c16 * 16];
      }
      #pragma unroll
      for (int mi = 0; mi < MF; mi++)
        #pragma unroll
        for (int ni = 0; ni < NF; ni++)
          acc[mi][ni] = __builtin_amdgcn_mfma_f32_16x16x32_bf16(af[mi], bf[ni], acc[mi][ni], 0, 0, 0);
    }
    __syncthreads();
  }

  const int g4 = (lane >> 4) * 4, cn = lane & 15;
  #pragma unroll
  for (int mi = 0; mi < MF; mi++) {
    #pragma unroll
    for (int reg = 0; reg < 4; reg++) {
      int r = wm * (BM / WM) + mi * 16 + g4 + reg;
      if (r < rv) {
        int aid = lst[r];
        #pragma unroll
        for (int ni = 0; ni < NF; ni++) {
          int n = nt * BN + wn * (BN / WN) + ni * 16 + cn;
          float v = acc[mi][ni][reg] + bias[(size_t)e * N + n];
          if constexpr (GELU) {
            v = 0.5f * v * (1.0f + erff(v * 0.70710678118654752f));
            ((unsigned short*)Out)[(size_t)aid * N + n] = f2bf(v);
          } else {
            ((float*)Out)[(size_t)aid * N + n] = v;
          }
        }
      }
    }
  }
}

// ---------------- combine top-2 rows (+ fused aux-loss finalize) ----------------
__global__ void k_combine(const float* __restrict__ buf, const float* __restrict__ topw,
                          float* __restrict__ out,
                          const int* __restrict__ cnt1, const float* __restrict__ psum,
                          const float* __restrict__ sqsum) {
  int i = blockIdx.x * 256 + threadIdx.x;
  int t = i >> 8, c = i & 255;
  float w0 = topw[2*t], w1 = topw[2*t + 1];
  float4 a = ((const float4*)(buf + (size_t)(2*t) * DDIM))[c];
  float4 b = ((const float4*)(buf + (size_t)(2*t + 1) * DDIM))[c];
  float4 o;
  o.x = w0*a.x + w1*b.x; o.y = w0*a.y + w1*b.y;
  o.z = w0*a.z + w1*b.z; o.w = w0*a.w + w1*b.w;
  ((float4*)out)[i] = o;
  if (i == 0) {
    float s = 0.f;
    for (int e = 0; e < NEXP; e++)
      s += ((float)cnt1[e] / (float)NTOK) * (psum[e] / (float)NTOK);
    out[(size_t)NTOK * DDIM] = (float)NEXP * s + (*sqsum) / (float)(NTOK * NEXP) * 1e-3f;
  }
}

extern "C" void kernel_launch(void* const* d_in, const int* in_sizes, int n_in,
                              void* d_out, int out_size, void* d_ws, size_t ws_size,
                              hipStream_t stream) {
  const float* x  = (const float*)d_in[0];
  const float* gw = (const float*)d_in[1];
  const float* w1 = (const float*)d_in[2];
  const float* b1 = (const float*)d_in[3];
  const float* w2 = (const float*)d_in[4];
  const float* b2 = (const float*)d_in[5];
  float* out = (float*)d_out;
  char* p = (char*)d_ws;

  // workspace layout (~136 MB)
  int*   ecnt  = (int*)p;                    // [8]
  int*   cnt1  = (int*)(p + 32);             // [8]
  float* psum  = (float*)(p + 64);           // [8]
  float* sqsum = (float*)(p + 96);           // [1]
  float* topw  = (float*)(p + 256);                            // 32 KB
  int*   elist = (int*)(p + 256 + 32768);                      // 128 KB
  unsigned short* xb  = (unsigned short*)(p + 256 + 32768 + 131072);   // 8 MB
  unsigned short* w1t = xb  + (size_t)NTOK * DDIM;                     // 32 MB  [E][F][D]
  unsigned short* w2t = w1t + (size_t)NEXP * DDIM * FDIM;              // 32 MB  [E][D][F]
  unsigned short* Hb  = w2t + (size_t)NEXP * DDIM * FDIM;              // 32 MB  [8192][F]
  float* obuf = (float*)(Hb + (size_t)NTOK * 2 * FDIM);                // 32 MB  [8192][D]

  hipMemsetAsync(p, 0, 128, stream);
  // prep (512 thr): router (blocks 0-255, quarter-D) + w1 transpose (256-1279)
  k_prep<<<256 + 1024, 512, 0, stream>>>(x, gw, w1, xb, w1t,
                                         topw, elist, ecnt, cnt1, psum, sqsum);
  // GEMM1 first (1280 blocks), then w2 transpose (1024 blocks, 512-thr) fills freed slots
  k_gemm1w2<<<NG1 + 1024, 512, 0, stream>>>(xb, w1t, b1, Hb, elist, ecnt, w2, w2t);
  // GEMM2 (XCD-chunked swizzle: expert-per-XCD, L2-resident B panel), 640 blocks
  k_gemm<FDIM, DDIM, false, false><<<(DDIM/128)*MTT*NEXP, 512, 0, stream>>>(Hb, w2t, b2, obuf, elist, ecnt);
  k_combine<<<NTOK * DDIM / 4 / 256, 256, 0, stream>>>(obuf, topw, out, cnt1, psum, sqsum);
}

// Round 21
// 231.411 us; speedup vs baseline: 1.0050x; 1.0050x over previous
//
#include <hip/hip_runtime.h>
#include <hip/hip_bf16.h>

#define NTOK 4096   // B*T
#define DDIM 1024
#define NEXP 8
#define FDIM 2048
#define CAP  4096   // max assignments per expert (list storage)
#define RTOK 16     // tokens per router block (512 threads, quarter-D split)
#define MTT  10     // m-tiles per expert (1280-row capacity; cnt~1024+-30, +8.5 sigma)

typedef float f32x4 __attribute__((ext_vector_type(4)));
typedef short s16x8 __attribute__((ext_vector_type(8)));
typedef short s16x4 __attribute__((ext_vector_type(4)));

__device__ __forceinline__ unsigned short f2bf(float f) {
  unsigned int u = __float_as_uint(f);
  unsigned int r = u + 0x7fffu + ((u >> 16) & 1u);
  return (unsigned short)(r >> 16);
}

__device__ __forceinline__ void gload16(const void* g, void* l) {
  __builtin_amdgcn_global_load_lds(
      (__attribute__((address_space(1))) unsigned int*)(g),
      (__attribute__((address_space(3))) unsigned int*)(l), 16, 0, 0);
}

// 512-thread transpose, ALL-LOADS-UPFRONT + 1 barrier/tile: src [R][C] f32 -> dst [C][R] bf16
// Block: 64 src-cols (c0) x 256 src-rows (r0b). All 8 global loads issued at entry ->
// first barrier's vmcnt(0) drains them concurrently (ONE exposed HBM latency, not four).
// Double-buffer [2][64][65]: single barrier per tile is WAR-safe (writers of buf b at
// iter t+2 execute after bar(t+1), whose arrivals post-date all iter-t reads of b).
// Load phase banks exact 2-way; store phase exact 2-way (free, m136).
__device__ __forceinline__ void transpose_tile512(const float* __restrict__ s,
                                                  unsigned short* __restrict__ d,
                                                  int R, int C, int c0, int r0b,
                                                  char* smem, int tid) {
  float (*tile)[64][65] = (float(*)[64][65])smem;
  const int lr = tid >> 4, lc = (tid & 15) * 4;     // lr 0..31
  const int sc = tid >> 3, sr = (tid & 7) * 8;      // sc 0..63
  float4 v[4][2];
  #pragma unroll
  for (int t = 0; t < 4; t++)
    #pragma unroll
    for (int p = 0; p < 2; p++)
      v[t][p] = *(const float4*)(s + (size_t)(r0b + t * 64 + p * 32 + lr) * C + c0 + lc);
  #pragma unroll
  for (int t = 0; t < 4; t++) {
    const int cur = t & 1;
    #pragma unroll
    for (int p = 0; p < 2; p++) {
      tile[cur][p * 32 + lr][lc]     = v[t][p].x;
      tile[cur][p * 32 + lr][lc + 1] = v[t][p].y;
      tile[cur][p * 32 + lr][lc + 2] = v[t][p].z;
      tile[cur][p * 32 + lr][lc + 3] = v[t][p].w;
    }
    __syncthreads();                                // publish writes (+drain loads once)
    const int r0 = r0b + t * 64;
    s16x8 o;
    #pragma unroll
    for (int j = 0; j < 8; j++) o[j] = (short)f2bf(tile[cur][sr + j][sc]);
    *(s16x8*)(d + (size_t)(c0 + sc) * R + r0 + sr) = o;   // 16B coalesced
  }
}

// ================= k_prep (512 thr): router (256 blocks, FIRST) + w1-transpose (1024 blocks) =================
// Router thread = (token t=tid>>5, quarter q=(tid>>3)&3, expert e=tid&7): 256-col fp64
// partial -> lgd[t][e][q]; serial chain 64 iters.
__global__ __launch_bounds__(512)
void k_prep(const float* __restrict__ x, const float* __restrict__ gw,
            const float* __restrict__ w1,
            unsigned short* __restrict__ xb, unsigned short* __restrict__ w1t,
            float* __restrict__ topw, int* __restrict__ elist,
            int* __restrict__ ecnt, int* __restrict__ cnt1,
            float* __restrict__ psum, float* __restrict__ sqsum) {
  __shared__ char smem[56320];   // union: transpose 33,280 | router ~54,100
  const int bid = blockIdx.x, tid = threadIdx.x;

  if (bid >= 256) {
    // ---- w1 transpose: [E][1024][2048] f32 -> w1t [E][2048][1024] bf16
    const int b = bid - 256;
    const int cx = b & 31, ry = (b >> 5) & 3, e = b >> 7;
    transpose_tile512(w1 + (size_t)e * DDIM * FDIM, w1t + (size_t)e * DDIM * FDIM,
                      DDIM, FDIM, cx * 64, ry * 256, smem, tid);
    return;
  }

  // ---- router: 256 blocks x 16 tokens; fp64 accum; emits xb ----
  float (*gwt)[DDIM + 4] = (float(*)[DDIM + 4])smem;          // 32,896 B
  float (*xs)[264]       = (float(*)[264])(smem + 32896);     // 16,896 B ([16][264])
  double (*lgd)[NEXP][4] = (double(*)[NEXP][4])(smem + 49792);// 4,096 B
  float* bps = (float*)(smem + 53888);
  int*   bc  = (int*)(smem + 53920);
  float* bsq = (float*)(smem + 53952);
  const int tok0 = bid * RTOK;

  for (int i = tid; i < DDIM * NEXP; i += 512) {
    int dd = i >> 3, ee = i & 7;
    gwt[ee][dd] = gw[i];
  }
  if (tid < NEXP) { bps[tid] = 0.f; bc[tid] = 0; }
  if (tid == 0) *bsq = 0.f;

  const int t = tid >> 5, q = (tid >> 3) & 3, e = tid & 7;
  double a0 = 0.0, a1 = 0.0, a2 = 0.0, a3 = 0.0;
  for (int c = 0; c < DDIM; c += 256) {
    __syncthreads();
    for (int i = tid; i < RTOK * 64; i += 512) {   // [16][256] chunk, float4 coalesced
      int r = i >> 6, c4 = i & 63;
      float4 v = *(const float4*)(x + (size_t)(tok0 + r) * DDIM + c + c4 * 4);
      *(float4*)&xs[r][c4 * 4] = v;
      s16x4 o;
      o[0] = (short)f2bf(v.x); o[1] = (short)f2bf(v.y);
      o[2] = (short)f2bf(v.z); o[3] = (short)f2bf(v.w);
      *(s16x4*)(xb + (size_t)(tok0 + r) * DDIM + c + c4 * 4) = o;
    }
    __syncthreads();
    if ((c >> 8) == q) {                           // my quarter only: 64 iters total
      #pragma unroll 8
      for (int d4 = 0; d4 < 64; d4++) {
        float4 xv = *(const float4*)&xs[t][d4 * 4];
        float4 gv = *(const float4*)&gwt[e][c + d4 * 4];
        a0 += (double)xv.x * (double)gv.x;
        a1 += (double)xv.y * (double)gv.y;
        a2 += (double)xv.z * (double)gv.z;
        a3 += (double)xv.w * (double)gv.w;
      }
    }
  }
  lgd[t][e][q] = (a0 + a1) + (a2 + a3);
  __syncthreads();

  if (tid < RTOK) {
    int tok = tok0 + tid;
    double acc[NEXP];
    #pragma unroll
    for (int k = 0; k < NEXP; k++)
      acc[k] = ((lgd[tid][k][0] + lgd[tid][k][1]) + lgd[tid][k][2]) + lgd[tid][k][3];
    int i0 = 0; double v0 = acc[0];
    #pragma unroll
    for (int k = 1; k < NEXP; k++) if (acc[k] > v0) { v0 = acc[k]; i0 = k; }
    int i1 = (i0 == 0) ? 1 : 0; double v1 = acc[i1];
    #pragma unroll
    for (int k = 0; k < NEXP; k++) if (k != i0 && acc[k] > v1) { v1 = acc[k]; i1 = k; }
    float w0 = 1.0f / (1.0f + expf((float)(v1 - v0)));   // softmax([v0,v1])[0]
    topw[2*tok] = w0; topw[2*tok + 1] = 1.0f - w0;
    int s0 = atomicAdd(&ecnt[i0], 1); elist[i0*CAP + s0] = 2*tok;
    int s1 = atomicAdd(&ecnt[i1], 1); elist[i1*CAP + s1] = 2*tok + 1;
    atomicAdd(&bc[i0], 1);
    float lm = (float)acc[0];
    #pragma unroll
    for (int k = 1; k < NEXP; k++) lm = fmaxf(lm, (float)acc[k]);
    float pe[NEXP], ps = 0.f, sq = 0.f;
    #pragma unroll
    for (int k = 0; k < NEXP; k++) {
      float le = (float)acc[k];
      pe[k] = expf(le - lm); ps += pe[k];
      sq += le * le;
    }
    float inv = 1.0f / ps;
    #pragma unroll
    for (int k = 0; k < NEXP; k++) atomicAdd(&bps[k], pe[k] * inv);
    atomicAdd(bsq, sq);
  }
  __syncthreads();
  if (tid < NEXP) { atomicAdd(&psum[tid], bps[tid]); atomicAdd(&cnt1[tid], bc[tid]); }
  if (tid == 0) atomicAdd(sqsum, *bsq);
}

// ================= k_gemm1w2: GEMM1 (1280 blocks, FIRST) + w2-transpose (1024 blocks, 512-thr) =================
#define NG1 (16 * MTT * NEXP)   // 1280 GEMM1 blocks
__global__ __launch_bounds__(512)
void k_gemm1w2(const unsigned short* __restrict__ A, const unsigned short* __restrict__ Bt,
               const float* __restrict__ bias, unsigned short* __restrict__ Out,
               const int* __restrict__ elist, const int* __restrict__ ecnt,
               const float* __restrict__ w2, unsigned short* __restrict__ w2t) {
  __shared__ char smem[65536];
  const int bid = blockIdx.x, tid = threadIdx.x;

  if (bid >= NG1) {
    // ---- w2 transpose: [E][2048][1024] f32 -> w2t [E][1024][2048] bf16
    const int b = bid - NG1;
    const int cx = b & 15, ry = (b >> 4) & 7, e = b >> 7;
    transpose_tile512(w2 + (size_t)e * FDIM * DDIM, w2t + (size_t)e * FDIM * DDIM,
                      FDIM, DDIM, cx * 64, ry * 256, smem, tid);
    return;
  }

  // ---- GEMM1 (R7/R17-proven mapping: nt fastest, then mt, then e — NO XCD swizzle) ----
  constexpr int K = DDIM, N = FDIM;
  constexpr int BM = 128, BN = 128, BK = 128, WM = 2, WN = 4;
  constexpr int GX = N / BN;                        // 16
  constexpr int AISS = 4, BISS = 4, MF = 4, NF = 2;
  unsigned char* lsA = (unsigned char*)smem;          // 32 KB
  unsigned char* lsB = (unsigned char*)smem + 32768;  // 32 KB

  const int w = bid;
  const int nt = w % GX;
  const int mt = (w / GX) % MTT;
  const int e  = w / (GX * MTT);

  const int cnt = ecnt[e];
  const int m0 = mt * BM;
  if (m0 >= cnt) return;
  const int rv = min(BM, cnt - m0);
  const int* lst = elist + e * CAP + m0;
  const int wv = tid >> 6, lane = tid & 63;
  const int wm = wv / WN, wn = wv % WN;
  const unsigned short* Be = Bt + (size_t)e * N * K;

  const unsigned short* agp[AISS];
  const unsigned short* bgp[BISS];
  int adst[AISS], bdst[BISS];
  const int cu = tid & 15;
  #pragma unroll
  for (int li = 0; li < AISS; li++) {
    int r = li * 32 + (tid >> 4);
    int rr = (r < rv) ? r : 0;
    int aid = lst[rr];
    int arow = aid >> 1;                            // ROWSHIFT
    agp[li] = A + (size_t)arow * K + (cu ^ (r & 15)) * 8;
    adst[li] = r * 256 + cu * 16;
  }
  #pragma unroll
  for (int li = 0; li < BISS; li++) {
    int r = li * 32 + (tid >> 4);
    bgp[li] = Be + (size_t)(nt * BN + r) * K + (cu ^ (r & 15)) * 8;
    bdst[li] = r * 256 + cu * 16;
  }

  f32x4 acc[MF][NF];
  #pragma unroll
  for (int mi = 0; mi < MF; mi++)
    #pragma unroll
    for (int ni = 0; ni < NF; ni++)
      acc[mi][ni] = (f32x4){0.f, 0.f, 0.f, 0.f};

  constexpr int NK = K / BK;
  for (int t = 0; t < NK; ++t) {
    const int k0 = t * BK;
    #pragma unroll
    for (int li = 0; li < AISS; li++) gload16(agp[li] + k0, &lsA[adst[li]]);
    #pragma unroll
    for (int li = 0; li < BISS; li++) gload16(bgp[li] + k0, &lsB[bdst[li]]);
    __syncthreads();
    #pragma unroll
    for (int ks = 0; ks < 4; ks++) {
      s16x8 af[MF], bf[NF];
      #pragma unroll
      for (int mi = 0; mi < MF; mi++) {
        int row = wm * (BM / WM) + mi * 16 + (lane & 15);
        int c16 = (ks * 4 + (lane >> 4)) ^ (row & 15);
        af[mi] = *(const s16x8*)&lsA[row * 256 + c16 * 16];
      }
      #pragma unroll
      for (int ni = 0; ni < NF; ni++) {
        int row = wn * (BN / WN) + ni * 16 + (lane & 15);
        int c16 = (ks * 4 + (lane >> 4)) ^ (row & 15);
        bf[ni] = *(const s16x8*)&lsB[row * 256 + c16 * 16];
      }
      #pragma unroll
      for (int mi = 0; mi < MF; mi++)
        #pragma unroll
        for (int ni = 0; ni < NF; ni++)
          acc[mi][ni] = __builtin_amdgcn_mfma_f32_16x16x32_bf16(af[mi], bf[ni], acc[mi][ni], 0, 0, 0);
    }
    __syncthreads();
  }

  const int g4 = (lane >> 4) * 4, cn = lane & 15;
  #pragma unroll
  for (int mi = 0; mi < MF; mi++) {
    #pragma unroll
    for (int reg = 0; reg < 4; reg++) {
      int r = wm * (BM / WM) + mi * 16 + g4 + reg;
      if (r < rv) {
        int aid = lst[r];
        #pragma unroll
        for (int ni = 0; ni < NF; ni++) {
          int n = nt * BN + wn * (BN / WN) + ni * 16 + cn;
          float v = acc[mi][ni][reg] + bias[(size_t)e * N + n];
          v = 0.5f * v * (1.0f + erff(v * 0.70710678118654752f));  // exact gelu
          Out[(size_t)aid * N + n] = f2bf(v);
        }
      }
    }
  }
}

// ---------------- GEMM2 (R16/R18-proven: XCD-chunked swizzle — expert-per-XCD, L2-resident B) ----------------
template<int K, int N, bool GELU, bool ROWSHIFT>
__global__ __launch_bounds__(512)
void k_gemm(const unsigned short* __restrict__ A, const unsigned short* __restrict__ Bt,
            const float* __restrict__ bias, void* __restrict__ Out,
            const int* __restrict__ elist, const int* __restrict__ ecnt) {
  constexpr int BM = 128, BN = 128, BK = 128, WM = 2, WN = 4;
  constexpr int GX = N / BN;
  constexpr int TOT = GX * MTT * NEXP;     // 640, % 8 == 0 (bijective)
  constexpr int CHUNK = TOT / 8;           // 80 = one expert's tile set
  constexpr int AISS = BM / 32, BISS = BN / 32;
  constexpr int MF = BM / WM / 16, NF = BN / WN / 16;
  __shared__ unsigned char lsA[BM * 256];
  __shared__ unsigned char lsB[BN * 256];

  const int w = blockIdx.x;
  const int swz = (w & 7) * CHUNK + (w >> 3);
  const int e = swz / CHUNK;
  const int loc = swz % CHUNK;
  const int mt = loc % MTT, nt = loc / MTT;

  const int cnt = ecnt[e];
  const int m0 = mt * BM;
  if (m0 >= cnt) return;
  const int rv = min(BM, cnt - m0);
  const int* lst = elist + e * CAP + m0;
  const int tid = threadIdx.x, wv = tid >> 6, lane = tid & 63;
  const int wm = wv / WN, wn = wv % WN;
  const unsigned short* Be = Bt + (size_t)e * N * K;

  const unsigned short* agp[AISS];
  const unsigned short* bgp[BISS];
  int adst[AISS], bdst[BISS];
  const int cu = tid & 15;
  #pragma unroll
  for (int li = 0; li < AISS; li++) {
    int r = li * 32 + (tid >> 4);
    int rr = (r < rv) ? r : 0;
    int aid = lst[rr];
    int arow = ROWSHIFT ? (aid >> 1) : aid;
    agp[li] = A + (size_t)arow * K + (cu ^ (r & 15)) * 8;
    adst[li] = r * 256 + cu * 16;
  }
  #pragma unroll
  for (int li = 0; li < BISS; li++) {
    int r = li * 32 + (tid >> 4);
    bgp[li] = Be + (size_t)(nt * BN + r) * K + (cu ^ (r & 15)) * 8;
    bdst[li] = r * 256 + cu * 16;
  }

  f32x4 acc[MF][NF];
  #pragma unroll
  for (int mi = 0; mi < MF; mi++)
    #pragma unroll
    for (int ni = 0; ni < NF; ni++)
      acc[mi][ni] = (f32x4){0.f, 0.f, 0.f, 0.f};

  constexpr int NK = K / BK;
  for (int t = 0; t < NK; ++t) {
    const int k0 = t * BK;
    #pragma unroll
    for (int li = 0; li < AISS; li++) gload16(agp[li] + k0, &lsA[adst[li]]);
    #pragma unroll
    for (int li = 0; li < BISS; li++) gload16(bgp[li] + k0, &lsB[bdst[li]]);
    __syncthreads();
    #pragma unroll
    for (int ks = 0; ks < 4; ks++) {
      s16x8 af[MF], bf[NF];
      #pragma unroll
      for (int mi = 0; mi < MF; mi++) {
        int row = wm * (BM / WM) + mi * 16 + (lane & 15);
        int c16 = (ks * 4 + (lane >> 4)) ^ (row & 15);
        af[mi] = *(const s16x8*)&lsA[row * 256 + c16 * 16];
      }
      #pragma unroll
      for (int ni = 0; ni < NF; ni++) {
        int row = wn * (BN / WN) + ni * 16 + (lane & 15);
        int c16 = (ks * 4 + (lane >> 4)) ^ (row & 15);
        bf[ni] = *(const s16x8*)&lsB[row * 256 + c16 * 16];
      }
      #pragma unroll
      for (int mi = 0; mi < MF; mi++)
        #pragma unroll
        for (int ni = 0; ni < NF; ni++)
          acc[mi][ni] = __builtin_amdgcn_mfma_f32_16x16x32_bf16(af[mi], bf[ni], acc[mi][ni], 0, 0, 0);
    }
    __syncthreads();
  }

  const int g4 = (lane >> 4) * 4, cn = lane & 15;
  #pragma unroll
  for (int mi = 0; mi < MF; mi++) {
    #pragma unroll
    for (int reg = 0; reg < 4; reg++) {
      int r = wm * (BM / WM) + mi * 16 + g4 + reg;
      if (r < rv) {
        int aid = lst[r];
        #pragma unroll
        for (int ni = 0; ni < NF; ni++) {
          int n = nt * BN + wn * (BN / WN) + ni * 16 + cn;
          float v = acc[mi][ni][reg] + bias[(size_t)e * N + n];
          if constexpr (GELU) {
            v = 0.5f * v * (1.0f + erff(v * 0.70710678118654752f));
            ((unsigned short*)Out)[(size_t)aid * N + n] = f2bf(v);
          } else {
            ((float*)Out)[(size_t)aid * N + n] = v;
          }
        }
      }
    }
  }
}

// ---------------- combine top-2 rows (+ fused aux-loss finalize) ----------------
__global__ void k_combine(const float* __restrict__ buf, const float* __restrict__ topw,
                          float* __restrict__ out,
                          const int* __restrict__ cnt1, const float* __restrict__ psum,
                          const float* __restrict__ sqsum) {
  int i = blockIdx.x * 256 + threadIdx.x;
  int t = i >> 8, c = i & 255;
  float w0 = topw[2*t], w1 = topw[2*t + 1];
  float4 a = ((const float4*)(buf + (size_t)(2*t) * DDIM))[c];
  float4 b = ((const float4*)(buf + (size_t)(2*t + 1) * DDIM))[c];
  float4 o;
  o.x = w0*a.x + w1*b.x; o.y = w0*a.y + w1*b.y;
  o.z = w0*a.z + w1*b.z; o.w = w0*a.w + w1*b.w;
  ((float4*)out)[i] = o;
  if (i == 0) {
    float s = 0.f;
    for (int e = 0; e < NEXP; e++)
      s += ((float)cnt1[e] / (float)NTOK) * (psum[e] / (float)NTOK);
    out[(size_t)NTOK * DDIM] = (float)NEXP * s + (*sqsum) / (float)(NTOK * NEXP) * 1e-3f;
  }
}

extern "C" void kernel_launch(void* const* d_in, const int* in_sizes, int n_in,
                              void* d_out, int out_size, void* d_ws, size_t ws_size,
                              hipStream_t stream) {
  const float* x  = (const float*)d_in[0];
  const float* gw = (const float*)d_in[1];
  const float* w1 = (const float*)d_in[2];
  const float* b1 = (const float*)d_in[3];
  const float* w2 = (const float*)d_in[4];
  const float* b2 = (const float*)d_in[5];
  float* out = (float*)d_out;
  char* p = (char*)d_ws;

  // workspace layout (~136 MB)
  int*   ecnt  = (int*)p;                    // [8]
  int*   cnt1  = (int*)(p + 32);             // [8]
  float* psum  = (float*)(p + 64);           // [8]
  float* sqsum = (float*)(p + 96);           // [1]
  float* topw  = (float*)(p + 256);                            // 32 KB
  int*   elist = (int*)(p + 256 + 32768);                      // 128 KB
  unsigned short* xb  = (unsigned short*)(p + 256 + 32768 + 131072);   // 8 MB
  unsigned short* w1t = xb  + (size_t)NTOK * DDIM;                     // 32 MB  [E][F][D]
  unsigned short* w2t = w1t + (size_t)NEXP * DDIM * FDIM;              // 32 MB  [E][D][F]
  unsigned short* Hb  = w2t + (size_t)NEXP * DDIM * FDIM;              // 32 MB  [8192][F]
  float* obuf = (float*)(Hb + (size_t)NTOK * 2 * FDIM);                // 32 MB  [8192][D]

  hipMemsetAsync(p, 0, 128, stream);
  // prep (512 thr): router (blocks 0-255, quarter-D) + w1 transpose (256-1279, all-loads-upfront)
  k_prep<<<256 + 1024, 512, 0, stream>>>(x, gw, w1, xb, w1t,
                                         topw, elist, ecnt, cnt1, psum, sqsum);
  // GEMM1 first (1280 blocks), then w2 transpose (1024 blocks) fills freed slots
  k_gemm1w2<<<NG1 + 1024, 512, 0, stream>>>(xb, w1t, b1, Hb, elist, ecnt, w2, w2t);
  // GEMM2 (XCD-chunked swizzle: expert-per-XCD, L2-resident B panel), 640 blocks
  k_gemm<FDIM, DDIM, false, false><<<(DDIM/128)*MTT*NEXP, 512, 0, stream>>>(Hb, w2t, b2, obuf, elist, ecnt);
  k_combine<<<NTOK * DDIM / 4 / 256, 256, 0, stream>>>(obuf, topw, out, cnt1, psum, sqsum);
}

// Round 22
// 227.388 us; speedup vs baseline: 1.0228x; 1.0177x over previous
//
#include <hip/hip_runtime.h>
#include <hip/hip_bf16.h>

#define NTOK 4096   // B*T
#define DDIM 1024
#define NEXP 8
#define FDIM 2048
#define CAP  4096   // max assignments per expert (list storage)
#define RTOK 8      // tokens per router block (512 threads, eighth-D split)
#define MTT  10     // m-tiles per expert (1280-row capacity; cnt~1024+-30, +8.5 sigma)

typedef float f32x4 __attribute__((ext_vector_type(4)));
typedef short s16x8 __attribute__((ext_vector_type(8)));
typedef short s16x4 __attribute__((ext_vector_type(4)));

__device__ __forceinline__ unsigned short f2bf(float f) {
  unsigned int u = __float_as_uint(f);
  unsigned int r = u + 0x7fffu + ((u >> 16) & 1u);
  return (unsigned short)(r >> 16);
}

__device__ __forceinline__ void gload16(const void* g, void* l) {
  __builtin_amdgcn_global_load_lds(
      (__attribute__((address_space(1))) unsigned int*)(g),
      (__attribute__((address_space(3))) unsigned int*)(l), 16, 0, 0);
}

// 512-thread transpose, ALL-LOADS-UPFRONT + 1 barrier/tile (R21-proven):
// src [R][C] f32 -> dst [C][R] bf16. Block: 64 src-cols x 256 src-rows, dbuf [2][64][65].
__device__ __forceinline__ void transpose_tile512(const float* __restrict__ s,
                                                  unsigned short* __restrict__ d,
                                                  int R, int C, int c0, int r0b,
                                                  char* smem, int tid) {
  float (*tile)[64][65] = (float(*)[64][65])smem;
  const int lr = tid >> 4, lc = (tid & 15) * 4;     // lr 0..31
  const int sc = tid >> 3, sr = (tid & 7) * 8;      // sc 0..63
  float4 v[4][2];
  #pragma unroll
  for (int t = 0; t < 4; t++)
    #pragma unroll
    for (int p = 0; p < 2; p++)
      v[t][p] = *(const float4*)(s + (size_t)(r0b + t * 64 + p * 32 + lr) * C + c0 + lc);
  #pragma unroll
  for (int t = 0; t < 4; t++) {
    const int cur = t & 1;
    #pragma unroll
    for (int p = 0; p < 2; p++) {
      tile[cur][p * 32 + lr][lc]     = v[t][p].x;
      tile[cur][p * 32 + lr][lc + 1] = v[t][p].y;
      tile[cur][p * 32 + lr][lc + 2] = v[t][p].z;
      tile[cur][p * 32 + lr][lc + 3] = v[t][p].w;
    }
    __syncthreads();                                // publish writes (+drain loads once)
    const int r0 = r0b + t * 64;
    s16x8 o;
    #pragma unroll
    for (int j = 0; j < 8; j++) o[j] = (short)f2bf(tile[cur][sr + j][sc]);
    *(s16x8*)(d + (size_t)(c0 + sc) * R + r0 + sr) = o;   // 16B coalesced
  }
}

// ======== k_prep (512 thr, 45.6KB LDS -> 3 blocks/CU): router (512 blocks) + w1-transpose (1024) ========
// Router thread = (token t=tid>>6, eighth s=(tid>>3)&7, expert e=tid&7): 128-col fp64
// partial -> lgd[t][e][s]; serial chain 32 iters.
__global__ __launch_bounds__(512)
void k_prep(const float* __restrict__ x, const float* __restrict__ gw,
            const float* __restrict__ w1,
            unsigned short* __restrict__ xb, unsigned short* __restrict__ w1t,
            float* __restrict__ topw, int* __restrict__ elist,
            int* __restrict__ ecnt, int* __restrict__ cnt1,
            float* __restrict__ psum, float* __restrict__ sqsum) {
  __shared__ char smem[45568];   // union: transpose 33,280 | router 45,508
  const int bid = blockIdx.x, tid = threadIdx.x;

  if (bid >= 512) {
    // ---- w1 transpose: [E][1024][2048] f32 -> w1t [E][2048][1024] bf16
    const int b = bid - 512;
    const int cx = b & 31, ry = (b >> 5) & 3, e = b >> 7;
    transpose_tile512(w1 + (size_t)e * DDIM * FDIM, w1t + (size_t)e * DDIM * FDIM,
                      DDIM, FDIM, cx * 64, ry * 256, smem, tid);
    return;
  }

  // ---- router: 512 blocks x 8 tokens; fp64 accum; emits xb ----
  float (*gwt)[DDIM + 4] = (float(*)[DDIM + 4])smem;          // 32,896 B (pad 4 -> 8 banks/expert)
  float (*xs)[264]       = (float(*)[264])(smem + 32896);     //  8,448 B ([8][264], pad 8)
  double (*lgd)[NEXP][8] = (double(*)[NEXP][8])(smem + 41344);//  4,096 B
  float* bps = (float*)(smem + 45440);
  int*   bc  = (int*)(smem + 45472);
  float* bsq = (float*)(smem + 45504);
  const int tok0 = bid * RTOK;

  for (int i = tid; i < DDIM * NEXP; i += 512) {
    int dd = i >> 3, ee = i & 7;
    gwt[ee][dd] = gw[i];
  }
  if (tid < NEXP) { bps[tid] = 0.f; bc[tid] = 0; }
  if (tid == 0) *bsq = 0.f;

  const int t = tid >> 6, s = (tid >> 3) & 7, e = tid & 7;
  const int h = s & 1;                               // half of the 256-col chunk
  double a0 = 0.0, a1 = 0.0, a2 = 0.0, a3 = 0.0;
  for (int c = 0; c < DDIM; c += 256) {
    __syncthreads();
    for (int i = tid; i < RTOK * 64; i += 512) {     // [8][256] chunk, float4 coalesced
      int r = i >> 6, c4 = i & 63;
      float4 v = *(const float4*)(x + (size_t)(tok0 + r) * DDIM + c + c4 * 4);
      *(float4*)&xs[r][c4 * 4] = v;
      s16x4 o;
      o[0] = (short)f2bf(v.x); o[1] = (short)f2bf(v.y);
      o[2] = (short)f2bf(v.z); o[3] = (short)f2bf(v.w);
      *(s16x4*)(xb + (size_t)(tok0 + r) * DDIM + c + c4 * 4) = o;
    }
    __syncthreads();
    if ((s >> 1) == (c >> 8)) {                      // my 128-col eighth: 32 iters total
      #pragma unroll 8
      for (int d4 = h * 32; d4 < h * 32 + 32; d4++) {
        float4 xv = *(const float4*)&xs[t][d4 * 4];
        float4 gv = *(const float4*)&gwt[e][c + d4 * 4];
        a0 += (double)xv.x * (double)gv.x;
        a1 += (double)xv.y * (double)gv.y;
        a2 += (double)xv.z * (double)gv.z;
        a3 += (double)xv.w * (double)gv.w;
      }
    }
  }
  lgd[t][e][s] = (a0 + a1) + (a2 + a3);
  __syncthreads();

  if (tid < RTOK) {
    int tok = tok0 + tid;
    double acc[NEXP];
    #pragma unroll
    for (int k = 0; k < NEXP; k++)
      acc[k] = ((lgd[tid][k][0] + lgd[tid][k][1]) + (lgd[tid][k][2] + lgd[tid][k][3]))
             + ((lgd[tid][k][4] + lgd[tid][k][5]) + (lgd[tid][k][6] + lgd[tid][k][7]));
    int i0 = 0; double v0 = acc[0];
    #pragma unroll
    for (int k = 1; k < NEXP; k++) if (acc[k] > v0) { v0 = acc[k]; i0 = k; }
    int i1 = (i0 == 0) ? 1 : 0; double v1 = acc[i1];
    #pragma unroll
    for (int k = 0; k < NEXP; k++) if (k != i0 && acc[k] > v1) { v1 = acc[k]; i1 = k; }
    float w0 = 1.0f / (1.0f + expf((float)(v1 - v0)));   // softmax([v0,v1])[0]
    topw[2*tok] = w0; topw[2*tok + 1] = 1.0f - w0;
    int s0 = atomicAdd(&ecnt[i0], 1); elist[i0*CAP + s0] = 2*tok;
    int s1 = atomicAdd(&ecnt[i1], 1); elist[i1*CAP + s1] = 2*tok + 1;
    atomicAdd(&bc[i0], 1);
    float lm = (float)acc[0];
    #pragma unroll
    for (int k = 1; k < NEXP; k++) lm = fmaxf(lm, (float)acc[k]);
    float pe[NEXP], ps = 0.f, sq = 0.f;
    #pragma unroll
    for (int k = 0; k < NEXP; k++) {
      float le = (float)acc[k];
      pe[k] = expf(le - lm); ps += pe[k];
      sq += le * le;
    }
    float inv = 1.0f / ps;
    #pragma unroll
    for (int k = 0; k < NEXP; k++) atomicAdd(&bps[k], pe[k] * inv);
    atomicAdd(bsq, sq);
  }
  __syncthreads();
  if (tid < NEXP) { atomicAdd(&psum[tid], bps[tid]); atomicAdd(&cnt1[tid], bc[tid]); }
  if (tid == 0) atomicAdd(sqsum, *bsq);
}

// ================= k_gemm1w2: GEMM1 (1280 blocks, FIRST) + w2-transpose (1024 blocks, 512-thr) =================
#define NG1 (16 * MTT * NEXP)   // 1280 GEMM1 blocks
__global__ __launch_bounds__(512)
void k_gemm1w2(const unsigned short* __restrict__ A, const unsigned short* __restrict__ Bt,
               const float* __restrict__ bias, unsigned short* __restrict__ Out,
               const int* __restrict__ elist, const int* __restrict__ ecnt,
               const float* __restrict__ w2, unsigned short* __restrict__ w2t) {
  __shared__ char smem[65536];
  const int bid = blockIdx.x, tid = threadIdx.x;

  if (bid >= NG1) {
    // ---- w2 transpose: [E][2048][1024] f32 -> w2t [E][1024][2048] bf16
    const int b = bid - NG1;
    const int cx = b & 15, ry = (b >> 4) & 7, e = b >> 7;
    transpose_tile512(w2 + (size_t)e * FDIM * DDIM, w2t + (size_t)e * FDIM * DDIM,
                      FDIM, DDIM, cx * 64, ry * 256, smem, tid);
    return;
  }

  // ---- GEMM1 (R7/R17-proven mapping: nt fastest, then mt, then e — NO XCD swizzle) ----
  constexpr int K = DDIM, N = FDIM;
  constexpr int BM = 128, BN = 128, BK = 128, WM = 2, WN = 4;
  constexpr int GX = N / BN;                        // 16
  constexpr int AISS = 4, BISS = 4, MF = 4, NF = 2;
  unsigned char* lsA = (unsigned char*)smem;          // 32 KB
  unsigned char* lsB = (unsigned char*)smem + 32768;  // 32 KB

  const int w = bid;
  const int nt = w % GX;
  const int mt = (w / GX) % MTT;
  const int e  = w / (GX * MTT);

  const int cnt = ecnt[e];
  const int m0 = mt * BM;
  if (m0 >= cnt) return;
  const int rv = min(BM, cnt - m0);
  const int* lst = elist + e * CAP + m0;
  const int wv = tid >> 6, lane = tid & 63;
  const int wm = wv / WN, wn = wv % WN;
  const unsigned short* Be = Bt + (size_t)e * N * K;

  const unsigned short* agp[AISS];
  const unsigned short* bgp[BISS];
  int adst[AISS], bdst[BISS];
  const int cu = tid & 15;
  #pragma unroll
  for (int li = 0; li < AISS; li++) {
    int r = li * 32 + (tid >> 4);
    int rr = (r < rv) ? r : 0;
    int aid = lst[rr];
    int arow = aid >> 1;                            // ROWSHIFT
    agp[li] = A + (size_t)arow * K + (cu ^ (r & 15)) * 8;
    adst[li] = r * 256 + cu * 16;
  }
  #pragma unroll
  for (int li = 0; li < BISS; li++) {
    int r = li * 32 + (tid >> 4);
    bgp[li] = Be + (size_t)(nt * BN + r) * K + (cu ^ (r & 15)) * 8;
    bdst[li] = r * 256 + cu * 16;
  }

  f32x4 acc[MF][NF];
  #pragma unroll
  for (int mi = 0; mi < MF; mi++)
    #pragma unroll
    for (int ni = 0; ni < NF; ni++)
      acc[mi][ni] = (f32x4){0.f, 0.f, 0.f, 0.f};

  constexpr int NK = K / BK;
  for (int t = 0; t < NK; ++t) {
    const int k0 = t * BK;
    #pragma unroll
    for (int li = 0; li < AISS; li++) gload16(agp[li] + k0, &lsA[adst[li]]);
    #pragma unroll
    for (int li = 0; li < BISS; li++) gload16(bgp[li] + k0, &lsB[bdst[li]]);
    __syncthreads();
    #pragma unroll
    for (int ks = 0; ks < 4; ks++) {
      s16x8 af[MF], bf[NF];
      #pragma unroll
      for (int mi = 0; mi < MF; mi++) {
        int row = wm * (BM / WM) + mi * 16 + (lane & 15);
        int c16 = (ks * 4 + (lane >> 4)) ^ (row & 15);
        af[mi] = *(const s16x8*)&lsA[row * 256 + c16 * 16];
      }
      #pragma unroll
      for (int ni = 0; ni < NF; ni++) {
        int row = wn * (BN / WN) + ni * 16 + (lane & 15);
        int c16 = (ks * 4 + (lane >> 4)) ^ (row & 15);
        bf[ni] = *(const s16x8*)&lsB[row * 256 + c16 * 16];
      }
      #pragma unroll
      for (int mi = 0; mi < MF; mi++)
        #pragma unroll
        for (int ni = 0; ni < NF; ni++)
          acc[mi][ni] = __builtin_amdgcn_mfma_f32_16x16x32_bf16(af[mi], bf[ni], acc[mi][ni], 0, 0, 0);
    }
    __syncthreads();
  }

  const int g4 = (lane >> 4) * 4, cn = lane & 15;
  #pragma unroll
  for (int mi = 0; mi < MF; mi++) {
    #pragma unroll
    for (int reg = 0; reg < 4; reg++) {
      int r = wm * (BM / WM) + mi * 16 + g4 + reg;
      if (r < rv) {
        int aid = lst[r];
        #pragma unroll
        for (int ni = 0; ni < NF; ni++) {
          int n = nt * BN + wn * (BN / WN) + ni * 16 + cn;
          float v = acc[mi][ni][reg] + bias[(size_t)e * N + n];
          v = 0.5f * v * (1.0f + erff(v * 0.70710678118654752f));  // exact gelu
          Out[(size_t)aid * N + n] = f2bf(v);
        }
      }
    }
  }
}

// ---------------- GEMM2 (R16/R18-proven: XCD-chunked swizzle — expert-per-XCD, L2-resident B) ----------------
template<int K, int N, bool GELU, bool ROWSHIFT>
__global__ __launch_bounds__(512)
void k_gemm(const unsigned short* __restrict__ A, const unsigned short* __restrict__ Bt,
            const float* __restrict__ bias, void* __restrict__ Out,
            const int* __restrict__ elist, const int* __restrict__ ecnt) {
  constexpr int BM = 128, BN = 128, BK = 128, WM = 2, WN = 4;
  constexpr int GX = N / BN;
  constexpr int TOT = GX * MTT * NEXP;     // 640, % 8 == 0 (bijective)
  constexpr int CHUNK = TOT / 8;           // 80 = one expert's tile set
  constexpr int AISS = BM / 32, BISS = BN / 32;
  constexpr int MF = BM / WM / 16, NF = BN / WN / 16;
  __shared__ unsigned char lsA[BM * 256];
  __shared__ unsigned char lsB[BN * 256];

  const int w = blockIdx.x;
  const int swz = (w & 7) * CHUNK + (w >> 3);
  const int e = swz / CHUNK;
  const int loc = swz % CHUNK;
  const int mt = loc % MTT, nt = loc / MTT;

  const int cnt = ecnt[e];
  const int m0 = mt * BM;
  if (m0 >= cnt) return;
  const int rv = min(BM, cnt - m0);
  const int* lst = elist + e * CAP + m0;
  const int tid = threadIdx.x, wv = tid >> 6, lane = tid & 63;
  const int wm = wv / WN, wn = wv % WN;
  const unsigned short* Be = Bt + (size_t)e * N * K;

  const unsigned short* agp[AISS];
  const unsigned short* bgp[BISS];
  int adst[AISS], bdst[BISS];
  const int cu = tid & 15;
  #pragma unroll
  for (int li = 0; li < AISS; li++) {
    int r = li * 32 + (tid >> 4);
    int rr = (r < rv) ? r : 0;
    int aid = lst[rr];
    int arow = ROWSHIFT ? (aid >> 1) : aid;
    agp[li] = A + (size_t)arow * K + (cu ^ (r & 15)) * 8;
    adst[li] = r * 256 + cu * 16;
  }
  #pragma unroll
  for (int li = 0; li < BISS; li++) {
    int r = li * 32 + (tid >> 4);
    bgp[li] = Be + (size_t)(nt * BN + r) * K + (cu ^ (r & 15)) * 8;
    bdst[li] = r * 256 + cu * 16;
  }

  f32x4 acc[MF][NF];
  #pragma unroll
  for (int mi = 0; mi < MF; mi++)
    #pragma unroll
    for (int ni = 0; ni < NF; ni++)
      acc[mi][ni] = (f32x4){0.f, 0.f, 0.f, 0.f};

  constexpr int NK = K / BK;
  for (int t = 0; t < NK; ++t) {
    const int k0 = t * BK;
    #pragma unroll
    for (int li = 0; li < AISS; li++) gload16(agp[li] + k0, &lsA[adst[li]]);
    #pragma unroll
    for (int li = 0; li < BISS; li++) gload16(bgp[li] + k0, &lsB[bdst[li]]);
    __syncthreads();
    #pragma unroll
    for (int ks = 0; ks < 4; ks++) {
      s16x8 af[MF], bf[NF];
      #pragma unroll
      for (int mi = 0; mi < MF; mi++) {
        int row = wm * (BM / WM) + mi * 16 + (lane & 15);
        int c16 = (ks * 4 + (lane >> 4)) ^ (row & 15);
        af[mi] = *(const s16x8*)&lsA[row * 256 + c16 * 16];
      }
      #pragma unroll
      for (int ni = 0; ni < NF; ni++) {
        int row = wn * (BN / WN) + ni * 16 + (lane & 15);
        int c16 = (ks * 4 + (lane >> 4)) ^ (row & 15);
        bf[ni] = *(const s16x8*)&lsB[row * 256 + c16 * 16];
      }
      #pragma unroll
      for (int mi = 0; mi < MF; mi++)
        #pragma unroll
        for (int ni = 0; ni < NF; ni++)
          acc[mi][ni] = __builtin_amdgcn_mfma_f32_16x16x32_bf16(af[mi], bf[ni], acc[mi][ni], 0, 0, 0);
    }
    __syncthreads();
  }

  const int g4 = (lane >> 4) * 4, cn = lane & 15;
  #pragma unroll
  for (int mi = 0; mi < MF; mi++) {
    #pragma unroll
    for (int reg = 0; reg < 4; reg++) {
      int r = wm * (BM / WM) + mi * 16 + g4 + reg;
      if (r < rv) {
        int aid = lst[r];
        #pragma unroll
        for (int ni = 0; ni < NF; ni++) {
          int n = nt * BN + wn * (BN / WN) + ni * 16 + cn;
          float v = acc[mi][ni][reg] + bias[(size_t)e * N + n];
          if constexpr (GELU) {
            v = 0.5f * v * (1.0f + erff(v * 0.70710678118654752f));
            ((unsigned short*)Out)[(size_t)aid * N + n] = f2bf(v);
          } else {
            ((float*)Out)[(size_t)aid * N + n] = v;
          }
        }
      }
    }
  }
}

// ---------------- combine top-2 rows (+ fused aux-loss finalize) ----------------
__global__ void k_combine(const float* __restrict__ buf, const float* __restrict__ topw,
                          float* __restrict__ out,
                          const int* __restrict__ cnt1, const float* __restrict__ psum,
                          const float* __restrict__ sqsum) {
  int i = blockIdx.x * 256 + threadIdx.x;
  int t = i >> 8, c = i & 255;
  float w0 = topw[2*t], w1 = topw[2*t + 1];
  float4 a = ((const float4*)(buf + (size_t)(2*t) * DDIM))[c];
  float4 b = ((const float4*)(buf + (size_t)(2*t + 1) * DDIM))[c];
  float4 o;
  o.x = w0*a.x + w1*b.x; o.y = w0*a.y + w1*b.y;
  o.z = w0*a.z + w1*b.z; o.w = w0*a.w + w1*b.w;
  ((float4*)out)[i] = o;
  if (i == 0) {
    float s = 0.f;
    for (int e = 0; e < NEXP; e++)
      s += ((float)cnt1[e] / (float)NTOK) * (psum[e] / (float)NTOK);
    out[(size_t)NTOK * DDIM] = (float)NEXP * s + (*sqsum) / (float)(NTOK * NEXP) * 1e-3f;
  }
}

extern "C" void kernel_launch(void* const* d_in, const int* in_sizes, int n_in,
                              void* d_out, int out_size, void* d_ws, size_t ws_size,
                              hipStream_t stream) {
  const float* x  = (const float*)d_in[0];
  const float* gw = (const float*)d_in[1];
  const float* w1 = (const float*)d_in[2];
  const float* b1 = (const float*)d_in[3];
  const float* w2 = (const float*)d_in[4];
  const float* b2 = (const float*)d_in[5];
  float* out = (float*)d_out;
  char* p = (char*)d_ws;

  // workspace layout (~136 MB)
  int*   ecnt  = (int*)p;                    // [8]
  int*   cnt1  = (int*)(p + 32);             // [8]
  float* psum  = (float*)(p + 64);           // [8]
  float* sqsum = (float*)(p + 96);           // [1]
  float* topw  = (float*)(p + 256);                            // 32 KB
  int*   elist = (int*)(p + 256 + 32768);                      // 128 KB
  unsigned short* xb  = (unsigned short*)(p + 256 + 32768 + 131072);   // 8 MB
  unsigned short* w1t = xb  + (size_t)NTOK * DDIM;                     // 32 MB  [E][F][D]
  unsigned short* w2t = w1t + (size_t)NEXP * DDIM * FDIM;              // 32 MB  [E][D][F]
  unsigned short* Hb  = w2t + (size_t)NEXP * DDIM * FDIM;              // 32 MB  [8192][F]
  float* obuf = (float*)(Hb + (size_t)NTOK * 2 * FDIM);                // 32 MB  [8192][D]

  hipMemsetAsync(p, 0, 128, stream);
  // prep (512 thr, 3 blk/CU): router (blocks 0-511, eighth-D) + w1 transpose (512-1535)
  k_prep<<<512 + 1024, 512, 0, stream>>>(x, gw, w1, xb, w1t,
                                         topw, elist, ecnt, cnt1, psum, sqsum);
  // GEMM1 first (1280 blocks), then w2 transpose (1024 blocks) fills freed slots
  k_gemm1w2<<<NG1 + 1024, 512, 0, stream>>>(xb, w1t, b1, Hb, elist, ecnt, w2, w2t);
  // GEMM2 (XCD-chunked swizzle: expert-per-XCD, L2-resident B panel), 640 blocks
  k_gemm<FDIM, DDIM, false, false><<<(DDIM/128)*MTT*NEXP, 512, 0, stream>>>(Hb, w2t, b2, obuf, elist, ecnt);
  k_combine<<<NTOK * DDIM / 4 / 256, 256, 0, stream>>>(obuf, topw, out, cnt1, psum, sqsum);
}